// Round 4
// baseline (39.420 us; speedup 1.0000x reference)
//
#include <hip/hip_runtime.h>

#define DEV __device__ __forceinline__

// Truncated level-3 signature state: s1[4], s2[16] (i*4+j), s3[64] (i*16+j*4+k).

// s <- s (x) exp(dx). 176 VALU ops.
// n3[ijk] = s3 + s2[ij]*dx[k] + (s1[i] + dx[i]/3) * (dx[j]*dx[k]/2)
// n2[ij]  = s2 + (s1[i] + dx[i]/2) * dx[j]
DEV void sig_step(float s1[4], float s2[16], float s3[64], const float dx[4]) {
    float w[16], u[4], g[4];
#pragma unroll
    for (int j = 0; j < 4; ++j) {
        float hj = 0.5f * dx[j];
        g[j] = s1[j] + hj;
        u[j] = fmaf(dx[j], (1.0f / 3.0f), s1[j]);
#pragma unroll
        for (int k = 0; k < 4; ++k) w[j * 4 + k] = hj * dx[k];
    }
#pragma unroll
    for (int i = 0; i < 4; ++i)
#pragma unroll
        for (int j = 0; j < 4; ++j)
#pragma unroll
            for (int k = 0; k < 4; ++k) {
                float v = s3[i * 16 + j * 4 + k];
                v = fmaf(s2[i * 4 + j], dx[k], v);
                v = fmaf(u[i], w[j * 4 + k], v);
                s3[i * 16 + j * 4 + k] = v;
            }
#pragma unroll
    for (int i = 0; i < 4; ++i)
#pragma unroll
        for (int j = 0; j < 4; ++j)
            s2[i * 4 + j] = fmaf(g[i], dx[j], s2[i * 4 + j]);
#pragma unroll
    for (int i = 0; i < 4; ++i) s1[i] += dx[i];
}

// s = exp(dx)  (first increment of a chunk)
DEV void sig_init(float s1[4], float s2[16], float s3[64], const float dx[4]) {
#pragma unroll
    for (int i = 0; i < 4; ++i) s1[i] = dx[i];
#pragma unroll
    for (int j = 0; j < 4; ++j) {
        float hj = 0.5f * dx[j];
#pragma unroll
        for (int k = 0; k < 4; ++k) s2[j * 4 + k] = hj * dx[k];
    }
#pragma unroll
    for (int i = 0; i < 4; ++i) {
        float ti = dx[i] * (1.0f / 3.0f);
#pragma unroll
        for (int jk = 0; jk < 16; ++jk) s3[i * 16 + jk] = ti * s2[jk];
    }
}

// a <- a (x) b, b read with stride 64 floats/term (works for LDS or global).
DEV void chen_fold(float a1[4], float a2[16], float a3[64], const float* __restrict__ b) {
    float b1[4], b2[16];
#pragma unroll
    for (int k = 0; k < 4; ++k) b1[k] = b[k * 64];
#pragma unroll
    for (int t = 0; t < 16; ++t) b2[t] = b[(4 + t) * 64];
#pragma unroll
    for (int i = 0; i < 4; ++i)
#pragma unroll
        for (int j = 0; j < 4; ++j)
#pragma unroll
            for (int k = 0; k < 4; ++k) {
                float v = a3[i * 16 + j * 4 + k] + b[(20 + i * 16 + j * 4 + k) * 64];
                v = fmaf(a2[i * 4 + j], b1[k], v);
                v = fmaf(a1[i], b2[j * 4 + k], v);
                a3[i * 16 + j * 4 + k] = v;
            }
#pragma unroll
    for (int i = 0; i < 4; ++i)
#pragma unroll
        for (int j = 0; j < 4; ++j)
            a2[i * 4 + j] = fmaf(a1[i], b1[j], a2[i * 4 + j] + b2[i * 4 + j]);
#pragma unroll
    for (int i = 0; i < 4; ++i) a1[i] += b1[i];
}

DEV void store_sig(float* dst, const float s1[4], const float s2[16], const float s3[64]) {
#pragma unroll
    for (int t = 0; t < 4; ++t) dst[t * 64] = s1[t];
#pragma unroll
    for (int t = 0; t < 16; ++t) dst[(4 + t) * 64] = s2[t];
#pragma unroll
    for (int t = 0; t < 64; ++t) dst[(20 + t) * 64] = s3[t];
}

DEV void load_sig(const float* src, float s1[4], float s2[16], float s3[64]) {
#pragma unroll
    for (int t = 0; t < 4; ++t) s1[t] = src[t * 64];
#pragma unroll
    for (int t = 0; t < 16; ++t) s2[t] = src[(4 + t) * 64];
#pragma unroll
    for (int t = 0; t < 64; ++t) s3[t] = src[(20 + t) * 64];
}

DEV void write_out(float* ob, const float s1[4], const float s2[16], const float s3[64]) {
#pragma unroll
    for (int t = 0; t < 4; ++t) ob[t] = s1[t];
#pragma unroll
    for (int t = 0; t < 16; ++t) ob[4 + t] = s2[t];
#pragma unroll
    for (int t = 0; t < 64; ++t) ob[20 + t] = s3[t];
}

// Geometry: B=64, T=1024, E=64, D=4.
// piece_kernel: block (256 thr = 4 waves) per (b, level-3 piece p). Wave w scans
// the 32-frame chunk c = 4p+w with a depth-4 rotating prefetch, then the block
// tree-folds 4 chunk sigs in LDS. Wave 0 writes l3sig/bdxl3 (ws) and out pg 7+p.
// waves_per_eu(2,2): PIN the budget to 256 VGPRs — min-only lets the compiler
// target higher occupancy and spill the 84-float state (R1-R3 evidence).
__global__ __attribute__((amdgpu_flat_work_group_size(256, 256),
                          amdgpu_waves_per_eu(2, 2)))
void piece_kernel(const float* __restrict__ x, float* __restrict__ l3sig,
                  float* __restrict__ bdxl3, float* __restrict__ out) {
    __shared__ float sigbuf[2][84][64];
    __shared__ float bdxs[4][4][64];
    const int b = blockIdx.x >> 3;
    const int p = blockIdx.x & 7;
    const int w = threadIdx.x >> 6;
    const int e = threadIdx.x & 63;
    const int c = p * 4 + w;
    // frame f of this chunk lives at xp[f * 64]
    const float4* xp = reinterpret_cast<const float4*>(x)
                     + (long)b * 65536 + (long)c * 32 * 64 + e;

    float4 prev = xp[0];
    if (c > 0) {  // boundary increment: last frame of chunk c-1 -> first of c
        float4 pm = xp[-64];
        float bx[4] = {prev.x - pm.x, prev.y - pm.y, prev.z - pm.z, prev.w - pm.w};
        if (w > 0) {
#pragma unroll
            for (int jj = 0; jj < 4; ++jj) bdxs[w][jj][e] = bx[jj];
        } else {  // level-3 piece boundary: export for treeB
            float* bb = &bdxl3[(((long)(b * 8 + p)) * 4) * 64 + e];
#pragma unroll
            for (int jj = 0; jj < 4; ++jj) bb[jj * 64] = bx[jj];
        }
    }

    // depth-4 rotating prefetch: buf[k] holds frame (k+1) initially
    float4 buf[4];
#pragma unroll
    for (int k = 0; k < 4; ++k) buf[k] = xp[(k + 1) * 64];

    float s1[4], s2[16], s3[64];
    {   // increment i=1 (slot 0)
        float4 cur = buf[0];
        float dx[4] = {cur.x - prev.x, cur.y - prev.y, cur.z - prev.z, cur.w - prev.w};
        sig_init(s1, s2, s3, dx);
        prev = cur;
        buf[0] = xp[5 * 64];
    }
    // increments i=2..29, 4-unrolled; load frame min(i+4,31) into the vacated slot
    for (int ii = 0; ii < 7; ++ii) {
#pragma unroll
        for (int j = 0; j < 4; ++j) {
            const int i = 2 + ii * 4 + j;
            const int slot = (j + 1) & 3;
            float4 cur = buf[slot];
            int li = i + 4; li = li > 31 ? 31 : li;
            buf[slot] = xp[li * 64];
            float dx[4] = {cur.x - prev.x, cur.y - prev.y, cur.z - prev.z, cur.w - prev.w};
            prev = cur;
            sig_step(s1, s2, s3, dx);
        }
    }
    // tail increments i=30 (slot 1), i=31 (slot 2); no more loads
#pragma unroll
    for (int j = 0; j < 2; ++j) {
        float4 cur = buf[1 + j];
        float dx[4] = {cur.x - prev.x, cur.y - prev.y, cur.z - prev.z, cur.w - prev.w};
        prev = cur;
        sig_step(s1, s2, s3, dx);
    }

    // round 1: waves 1,3 publish; waves 0,2 fold (join via boundary dx)
    if (w == 1 || w == 3) store_sig(&sigbuf[w >> 1][0][e], s1, s2, s3);
    __syncthreads();
    if (w == 0 || w == 2) {
        float dxl[4] = {bdxs[w + 1][0][e], bdxs[w + 1][1][e], bdxs[w + 1][2][e], bdxs[w + 1][3][e]};
        sig_step(s1, s2, s3, dxl);
        chen_fold(s1, s2, s3, &sigbuf[w >> 1][0][e]);
    }
    __syncthreads();
    // round 2: wave 2 publishes; wave 0 folds -> full level-3 piece
    if (w == 2) store_sig(&sigbuf[0][0][e], s1, s2, s3);
    __syncthreads();
    if (w == 0) {
        float dxl[4] = {bdxs[2][0][e], bdxs[2][1][e], bdxs[2][2][e], bdxs[2][3][e]};
        sig_step(s1, s2, s3, dxl);
        chen_fold(s1, s2, s3, &sigbuf[0][0][e]);
        store_sig(&l3sig[(((long)(b * 8 + p)) * 84) * 64 + e], s1, s2, s3);
        write_out(&out[(((long)(b * 64 + e)) * 15 + 7 + p) * 84], s1, s2, s3);
    }
}

// treeB: one block (4 waves) per b. Round 1 -> pg3..6 (pair folds), round 2 ->
// pg1,pg2, round 3 -> pg0. waves_per_eu(1,1) pins a 512-VGPR budget (no spill).
__global__ __attribute__((amdgpu_flat_work_group_size(256, 256),
                          amdgpu_waves_per_eu(1, 1)))
void treeB_kernel(const float* __restrict__ l3sig, const float* __restrict__ bdxl3,
                  float* __restrict__ out) {
    __shared__ float sigbuf[2][84][64];
    const int b = blockIdx.x;
    const int w = threadIdx.x >> 6;
    const int e = threadIdx.x & 63;

    float s1[4], s2[16], s3[64];
    // round 1: wave w folds pieces (2w, 2w+1) -> pg 3+w
    load_sig(&l3sig[(((long)(b * 8 + 2 * w)) * 84) * 64 + e], s1, s2, s3);
    {
        const float* bb = &bdxl3[(((long)(b * 8 + 2 * w + 1)) * 4) * 64 + e];
        float dx[4] = {bb[0], bb[64], bb[128], bb[192]};
        sig_step(s1, s2, s3, dx);
        chen_fold(s1, s2, s3, &l3sig[(((long)(b * 8 + 2 * w + 1)) * 84) * 64 + e]);
    }
    write_out(&out[(((long)(b * 64 + e)) * 15 + 3 + w) * 84], s1, s2, s3);

    if (w == 1 || w == 3) store_sig(&sigbuf[w >> 1][0][e], s1, s2, s3);
    __syncthreads();
    // round 2: wave 0 -> pg1 (pieces 0..3), wave 2 -> pg2 (pieces 4..7)
    if (w == 0 || w == 2) {
        const int jp = (w == 0) ? 2 : 6;  // first piece of the right half
        const float* bb = &bdxl3[(((long)(b * 8 + jp)) * 4) * 64 + e];
        float dx[4] = {bb[0], bb[64], bb[128], bb[192]};
        sig_step(s1, s2, s3, dx);
        chen_fold(s1, s2, s3, &sigbuf[w >> 1][0][e]);
        write_out(&out[(((long)(b * 64 + e)) * 15 + 1 + (w >> 1)) * 84], s1, s2, s3);
    }
    __syncthreads();
    // round 3: wave 2 publishes; wave 0 -> pg0 (pieces 0..7)
    if (w == 2) store_sig(&sigbuf[0][0][e], s1, s2, s3);
    __syncthreads();
    if (w == 0) {
        const float* bb = &bdxl3[(((long)(b * 8 + 4)) * 4) * 64 + e];
        float dx[4] = {bb[0], bb[64], bb[128], bb[192]};
        sig_step(s1, s2, s3, dx);
        chen_fold(s1, s2, s3, &sigbuf[0][0][e]);
        write_out(&out[(((long)(b * 64 + e)) * 15 + 0) * 84], s1, s2, s3);
    }
}

// Fallback: direct sequential scan per (b, piece) — only if ws is too small.
__global__ __attribute__((amdgpu_flat_work_group_size(64, 64),
                          amdgpu_waves_per_eu(1, 1)))
void direct_kernel(const float* __restrict__ x, float* __restrict__ out) {
    const int pg = blockIdx.x % 15;
    const int b = blockIdx.x / 15;
    const int e = threadIdx.x;
    int lvl, p;
    if (pg == 0)      { lvl = 0; p = 0; }
    else if (pg < 3)  { lvl = 1; p = pg - 1; }
    else if (pg < 7)  { lvl = 2; p = pg - 3; }
    else              { lvl = 3; p = pg - 7; }
    const int L = 1024 >> lvl;
    const int t0 = p * L;
    const float4* xf = reinterpret_cast<const float4*>(x);
    const long base = (long)b * 65536;

    float4 prev = xf[base + (long)t0 * 64 + e];
    float s1[4], s2[16], s3[64];
    {
        float4 cur = xf[base + (long)(t0 + 1) * 64 + e];
        float dx[4] = {cur.x - prev.x, cur.y - prev.y, cur.z - prev.z, cur.w - prev.w};
        sig_init(s1, s2, s3, dx);
        prev = cur;
    }
    for (int i = 2; i < L; ++i) {
        float4 cur = xf[base + (long)(t0 + i) * 64 + e];
        float dx[4] = {cur.x - prev.x, cur.y - prev.y, cur.z - prev.z, cur.w - prev.w};
        prev = cur;
        sig_step(s1, s2, s3, dx);
    }
    write_out(&out[(((long)(b * 64 + e)) * 15 + pg) * 84], s1, s2, s3);
}

extern "C" void kernel_launch(void* const* d_in, const int* in_sizes, int n_in,
                              void* d_out, int out_size, void* d_ws, size_t ws_size,
                              hipStream_t stream) {
    (void)in_sizes; (void)n_in; (void)out_size;
    const float* x = (const float*)d_in[0];
    float* out = (float*)d_out;

    const size_t l3_elems = (size_t)64 * 8 * 84 * 64;
    const size_t bdx_elems = (size_t)64 * 8 * 4 * 64;
    const size_t need = (l3_elems + bdx_elems) * sizeof(float);

    if (ws_size >= need) {
        float* l3sig = (float*)d_ws;
        float* bdxl3 = l3sig + l3_elems;
        piece_kernel<<<64 * 8, 256, 0, stream>>>(x, l3sig, bdxl3, out);
        treeB_kernel<<<64, 256, 0, stream>>>(l3sig, bdxl3, out);
    } else {
        direct_kernel<<<64 * 15, 64, 0, stream>>>(x, out);
    }
}